// Round 3
// baseline (80.324 us; speedup 1.0000x reference)
//
#include <hip/hip_runtime.h>

// Problem constants (fixed by setup_inputs): depth (16,1,512,512) fp32, W (8,8) fp32.
// Output (16,3,512,512) fp32.
//
// Math reduction: out[b,c,h,w] = sign(depth[b,0,h,w]) * W[0,1+c] / ||W[0,1:4]||
// (0 where depth==0). The Euler scan factor (1-0.9^10) and spectral-norm
// scaling 1/sigma are positive scalars that cancel in the L2 normalization.
// Pure bandwidth kernel: 16.8MB read + 50.3MB write, floor ~11us @ 6.1 TB/s.
//
// R2: nontemporal builtins need native vector types, not HIP_vector_type
// structs — use ext_vector_type(4) float.

constexpr int HW    = 512 * 512;   // 262144 (divisible by 4 -> float4 never crosses image)
constexpr int BATCH = 16;
constexpr int NPIX  = BATCH * HW;  // 4194304

typedef float f32x4 __attribute__((ext_vector_type(4)));

__global__ __launch_bounds__(256)
void scene_normal_kernel(const float* __restrict__ depth,
                         const float* __restrict__ Wm,
                         float* __restrict__ out)
{
    // W row-major 8x8: row 0, cols 1..3
    const float w0 = Wm[1], w1 = Wm[2], w2 = Wm[3];
    const float inv = rsqrtf(w0 * w0 + w1 * w1 + w2 * w2);
    const float n0 = w0 * inv, n1 = w1 * inv, n2 = w2 * inv;

    const int idx4 = blockIdx.x * blockDim.x + threadIdx.x;  // float4 group index
    const int p = idx4 * 4;                                  // pixel index
    if (p >= NPIX) return;

    const f32x4* dp = reinterpret_cast<const f32x4*>(depth + p);
    const f32x4 x4 = __builtin_nontemporal_load(dp);

    f32x4 s;
#pragma unroll
    for (int i = 0; i < 4; ++i)
        s[i] = (x4[i] > 0.0f) ? 1.0f : ((x4[i] < 0.0f) ? -1.0f : 0.0f);

    const int b = p >> 18;         // p / HW  (HW = 2^18)
    const int q = p & (HW - 1);    // pixel within image (multiple of 4)
    float* obase = out + (size_t)b * 3 * HW + q;

    __builtin_nontemporal_store(s * n0, reinterpret_cast<f32x4*>(obase));
    __builtin_nontemporal_store(s * n1, reinterpret_cast<f32x4*>(obase + HW));
    __builtin_nontemporal_store(s * n2, reinterpret_cast<f32x4*>(obase + 2 * HW));
}

extern "C" void kernel_launch(void* const* d_in, const int* in_sizes, int n_in,
                              void* d_out, int out_size, void* d_ws, size_t ws_size,
                              hipStream_t stream)
{
    const float* depth = (const float*)d_in[0];  // 16*1*512*512 fp32
    const float* Wm    = (const float*)d_in[1];  // 8*8 fp32
    float* out = (float*)d_out;                  // 16*3*512*512 fp32

    const int groups = NPIX / 4;                 // 1,048,576 float4 groups
    const int block = 256;
    const int grid = (groups + block - 1) / block;  // 4096 blocks
    scene_normal_kernel<<<grid, block, 0, stream>>>(depth, Wm, out);
}